// Round 11
// baseline (2555.275 us; speedup 1.0000x reference)
//
#include <hip/hip_runtime.h>
#include <hip/hip_bf16.h>

// GRU forward: B=64, T=512, I=512, U=512, out [B,T,U] fp32.
// Round 11 = round 10 (tag-in-data, 2-barrier step, 2033us scan) + two fixes:
//  (1) staging/polling moved ENTIRELY to waves 4-7 (16 u64/thread over 4
//      conflict-free regions). r10 had gate waves (0-3) also staging: after
//      B(t) they issued h-store + out-store(HBM) then their A1 spin's first
//      s_waitcnt vmcnt(0) waited those STORE ACKS (~1-2us) before the first
//      poll could even complete. Waves 4-7 are idle during gates -> they now
//      spin BEFORE producers store; gate waves skip A1 and never wait their
//      own store acks (wg_barrier waits lgkmcnt only).
//  (2) xgemm reshaped: 2 row-tiles x 8 col-tiles per wave (grid 3072 = 1024
//      row-pairs x 3 col-groups) -> each B-frag load feeds 6 MFMAs, weight
//      L2 traffic halves (6.1 -> 3 GB).
// Protocol recap: gates store h as one atomic u64 {hi0,hi1,lo0,lo1} with
// 2-bit tag (t%3)+1 in the two lo-bf16 LSBs (err<=2^-16), fire-and-forget;
// staging waves spin until all 16 of their slots carry the tag -> detect IS
// the load. Raw s_barrier + lgkmcnt(0) only. __launch_bounds__(512,1).

typedef float f32x4 __attribute__((ext_vector_type(4)));
typedef float f32x2 __attribute__((ext_vector_type(2)));
typedef short bf16x8 __attribute__((ext_vector_type(8)));
typedef unsigned long long u64;
typedef unsigned int u32;
typedef unsigned short u16;
typedef u32 u32x4 __attribute__((ext_vector_type(4)));

#define MFMA16(a, b, c) __builtin_amdgcn_mfma_f32_16x16x32_bf16((a), (b), (c), 0, 0, 0)

__device__ __forceinline__ float bf2f(__hip_bfloat16 v) { return __bfloat162float(v); }

__device__ __forceinline__ void split_bf(float v, short& hi, short& lo) {
    __hip_bfloat16 h = __float2bfloat16(v);
    float rem = v - __bfloat162float(h);
    __hip_bfloat16 l = __float2bfloat16(rem);
    hi = __builtin_bit_cast(short, h);
    lo = __builtin_bit_cast(short, l);
}

// Raw barrier: LDS-drain only. No vmcnt drain (that's the point).
__device__ __forceinline__ void wg_barrier() {
    __builtin_amdgcn_sched_barrier(0);
    asm volatile("s_waitcnt lgkmcnt(0)" ::: "memory");
    __builtin_amdgcn_s_barrier();
    __builtin_amdgcn_sched_barrier(0);
}

// ---------------------------------------------------------------- zero scratch
__global__ void zero_kernel(float* p, int n) {
    int i = blockIdx.x * blockDim.x + threadIdx.x;
    int stride = gridDim.x * blockDim.x;
    for (; i < n; i += stride) p[i] = 0.f;
}

// ------------------------------------------------- pack weights into B-frags
// Source W [512 x 1536] fp32. Frag (tile,kk): lane l element e =
// W[kk*32 + 8*(l>>4) + e][tile*16 + (l&15)], stored hi/lo bf16 planes.
__global__ __launch_bounds__(64, 1) void pack_w_kernel(const float* __restrict__ W,
                                                       short* __restrict__ dhi,
                                                       short* __restrict__ dlo) {
    int bid = blockIdx.x;   // tile*16 + kk, 0..1535
    int lane = threadIdx.x; // 0..63
    int col = (bid >> 4) * 16 + (lane & 15);
    int kbase = (bid & 15) * 32 + (lane >> 4) * 8;
    bf16x8 vh, vl;
#pragma unroll
    for (int e = 0; e < 8; e++) {
        float v = W[(kbase + e) * 1536 + col];
        short h, l;
        split_bf(v, h, l);
        vh[e] = h;
        vl[e] = l;
    }
    *(bf16x8*)(dhi + bid * 512 + lane * 8) = vh;
    *(bf16x8*)(dlo + bid * 512 + lane * 8) = vl;
}

// ------------------------------------------------------------- x_all GEMM
// 3072 blocks = 1024 row-pairs x 3 col-groups. Block: rows rp*32..+31,
// cols cg*512..+511. Wave: 2 row-tiles x 8 col-tiles; each B-frag load feeds
// 6 MFMAs (2 rows x 3 hi/lo passes).
__global__ __launch_bounds__(256, 2) void xgemm_kernel(
    const float* __restrict__ A, const short* __restrict__ wkh,
    const short* __restrict__ wkl, const float* __restrict__ bias,
    __hip_bfloat16* __restrict__ xhi, __hip_bfloat16* __restrict__ xlo, int xlo_en) {
    int bid = blockIdx.x; // 0..3071
    int cg = bid % 3;
    int rp = bid / 3;
    int wave = threadIdx.x >> 6, lane = threadIdx.x & 63;
    int arow0 = rp * 32 + (lane & 15);
    const float* ab0 = A + (size_t)arow0 * 512 + (lane >> 4) * 8;
    const float* ab1 = ab0 + 16 * 512;

    f32x4 acc[2][8];
#pragma unroll
    for (int r = 0; r < 2; r++)
#pragma unroll
        for (int j = 0; j < 8; j++) acc[r][j] = (f32x4){0.f, 0.f, 0.f, 0.f};

#pragma unroll 1
    for (int kk = 0; kk < 16; kk++) {
        f32x4 a00 = *(const f32x4*)(ab0 + kk * 32);
        f32x4 a01 = *(const f32x4*)(ab0 + kk * 32 + 4);
        f32x4 a10 = *(const f32x4*)(ab1 + kk * 32);
        f32x4 a11 = *(const f32x4*)(ab1 + kk * 32 + 4);
        bf16x8 ah0, al0, ah1, al1;
#pragma unroll
        for (int e = 0; e < 8; e++) {
            float v0 = (e < 4) ? a00[e] : a01[e - 4];
            float v1 = (e < 4) ? a10[e] : a11[e - 4];
            short h, l;
            split_bf(v0, h, l);
            ah0[e] = h;
            al0[e] = l;
            split_bf(v1, h, l);
            ah1[e] = h;
            al1[e] = l;
        }
#pragma unroll
        for (int j = 0; j < 8; j++) {
            int frag = (cg * 32 + wave * 8 + j) * 16 + kk;
            bf16x8 bh = *(const bf16x8*)(wkh + frag * 512 + lane * 8);
            bf16x8 bl = *(const bf16x8*)(wkl + frag * 512 + lane * 8);
            acc[0][j] = MFMA16(ah0, bh, acc[0][j]);
            acc[0][j] = MFMA16(al0, bh, acc[0][j]);
            acc[0][j] = MFMA16(ah0, bl, acc[0][j]);
            acc[1][j] = MFMA16(ah1, bh, acc[1][j]);
            acc[1][j] = MFMA16(al1, bh, acc[1][j]);
            acc[1][j] = MFMA16(ah1, bl, acc[1][j]);
        }
    }
    int colin = lane & 15, r4 = (lane >> 4) * 4;
#pragma unroll
    for (int j = 0; j < 8; j++) {
        int colg = (cg * 32 + wave * 8 + j) * 16 + colin;
        float bv = bias[colg];
#pragma unroll
        for (int rt = 0; rt < 2; rt++) {
#pragma unroll
            for (int r = 0; r < 4; r++) {
                float v = acc[rt][j][r] + bv;
                int rowg = rp * 32 + rt * 16 + r4 + r;
                short h, l;
                split_bf(v, h, l);
                xhi[(size_t)rowg * 1536 + colg] = __builtin_bit_cast(__hip_bfloat16, h);
                if (xlo_en)
                    xlo[(size_t)rowg * 1536 + colg] =
                        __builtin_bit_cast(__hip_bfloat16, l);
            }
        }
    }
}

// ------------------------------------------------------------------ scan
// hbuf2 layout: [par(2)][group(4)][4096 u64]; slot s within a group:
// chunk=s>>8 (peer WG w), lane'=(s>>2)&63, epair=s&3. u64 = {hi0,hi1,lo0,lo1}
// for (row=lane'&15, units 32*chunk + 8*(lane'>>4) + 2*epair..+1), tag bits
// in lo0/lo1 LSBs. hsh u32 view: hshu[par*8192 + plane*4096 + s].
__global__ __launch_bounds__(512, 1) void scan_kernel(
    const __hip_bfloat16* __restrict__ xhi, const __hip_bfloat16* __restrict__ xlo,
    const short* __restrict__ wrh, const short* __restrict__ wrl,
    const float* __restrict__ bias, float* __restrict__ out,
    u64* hbuf2, int xlo_en) {
    const int bid = blockIdx.x;
    const int g = bid & 3;
    const int w = bid >> 2;
    const int tid = threadIdx.x;
    const int wave = tid >> 6;
    const int lane = tid & 63;

    __shared__ __align__(16) float pre[6][16][16];
    __shared__ __align__(16) __hip_bfloat16 xsh[2][2][16][104]; // [par][plane]
    __shared__ __align__(16) __hip_bfloat16 hsh[2][2][16][512]; // [par][plane][kk][frag]
    __shared__ float rb[96];

    if (tid < 96) rb[tid] = bias[1536 + (tid >> 5) * 512 + w * 32 + (tid & 31)];

    // persistent B fragments (hi+lo) for waves 0-5 (LB(512,1): stays resident)
    bf16x8 bh[16], bl[16];
    if (wave < 6) {
        int tile = (wave >> 1) * 32 + 2 * w + (wave & 1);
#pragma unroll
        for (int kk = 0; kk < 16; kk++) {
            bh[kk] = *(const bf16x8*)(wrh + (tile * 16 + kk) * 512 + lane * 8);
            bl[kk] = *(const bf16x8*)(wrl + (tile * 16 + kk) * 512 + lane * 8);
        }
#pragma unroll
        for (int kk = 0; kk < 16; kk++) {
            asm volatile("" : "+v"(bh[kk]), "+v"(bl[kk])); // defeat remat
        }
    }
    if (wave >= 6) {
        // x[0] prefetch straight into xsh[0]
        int it0 = tid - 384; // 0..127
        int nch = xlo_en ? 384 : 192;
        for (int c = it0; c < nch; c += 128) {
            int plane = c / 192, rem = c % 192;
            int row_ = rem / 12, cw = rem % 12;
            const __hip_bfloat16* src = (plane ? xlo : xhi) +
                                        (size_t)((g * 16 + row_) * 512) * 1536 +
                                        (cw >> 2) * 512 + w * 32 + (cw & 3) * 8;
            *(bf16x8*)&xsh[0][plane][row_][(cw >> 2) * 32 + (cw & 3) * 8] =
                *(const bf16x8*)src;
        }
    }

    const int grow = tid & 15; // gate thread: batch row
    const int q = tid >> 4;    // gate thread: unit pair 0..15 (tid<256)
    float h0 = 0.f, h1 = 0.f;
    const int hslot = w * 256 + (grow + 16 * (q >> 2)) * 4 + (q & 3);
    const int st = tid - 256;  // staging thread index 0..255 (waves 4-7)
    const int xit = tid - 384; // x-prefetch thread index (waves 6-7)

    u32* hshu = (u32*)hsh;

    __syncthreads();

    for (int t = 0; t < 512; t++) {
        const int par = t & 1;
        // ===== A1: waves 4-7 poll + stage h; waves 0-3 go straight to bar ====
        if (wave >= 4) {
            // x[t+1] loads issued first (stay outstanding through the spin)
            bf16x8 xv0, xv1, xv2;
            if (wave >= 6 && t + 1 < 512) {
                int c0 = xit, c1 = xit + 128, c2 = xit + 256;
                {
                    int plane = c0 / 192, rem = c0 % 192, row_ = rem / 12,
                        cw = rem % 12;
                    xv0 = *(const bf16x8*)((plane ? xlo : xhi) +
                                           (size_t)((g * 16 + row_) * 512 + (t + 1)) *
                                               1536 +
                                           (cw >> 2) * 512 + w * 32 + (cw & 3) * 8);
                }
                if (xlo_en || c1 < 192) {
                    int plane = c1 / 192, rem = c1 % 192, row_ = rem / 12,
                        cw = rem % 12;
                    xv1 = *(const bf16x8*)((plane ? xlo : xhi) +
                                           (size_t)((g * 16 + row_) * 512 + (t + 1)) *
                                               1536 +
                                           (cw >> 2) * 512 + w * 32 + (cw & 3) * 8);
                }
                if (xlo_en) {
                    int plane = 1, rem = c2 % 192, row_ = rem / 12, cw = rem % 12;
                    xv2 = *(const bf16x8*)((plane ? xlo : xhi) +
                                           (size_t)((g * 16 + row_) * 512 + (t + 1)) *
                                               1536 +
                                           (cw >> 2) * 512 + w * 32 + (cw & 3) * 8);
                }
            }
            // poll 16 slots (4 conflict-free regions x 4 consecutive u64)
            u64 sv[16];
            {
                const u64* gb = hbuf2 + ((size_t)(((t - 1) & 1) * 4 + g)) * 4096;
                if (t == 0) {
#pragma unroll
                    for (int r = 0; r < 4; r++)
#pragma unroll
                        for (int j = 0; j < 4; j++)
                            sv[r * 4 + j] =
                                __hip_atomic_load(gb + r * 1024 + st * 4 + j,
                                                  __ATOMIC_RELAXED,
                                                  __HIP_MEMORY_SCOPE_AGENT);
                } else {
                    const int expv = ((t - 1) % 3) + 1;
                    const u64 expm =
                        ((u64)(expv & 1) << 32) | ((u64)((expv >> 1) & 1) << 48);
                    const u64 TAGM = (1ULL << 32) | (1ULL << 48);
                    long spins = 0;
                    while (true) {
#pragma unroll
                        for (int r = 0; r < 4; r++)
#pragma unroll
                            for (int j = 0; j < 4; j++)
                                sv[r * 4 + j] =
                                    __hip_atomic_load(gb + r * 1024 + st * 4 + j,
                                                      __ATOMIC_RELAXED,
                                                      __HIP_MEMORY_SCOPE_AGENT);
                        u64 diff = 0;
#pragma unroll
                        for (int k = 0; k < 16; k++) diff |= (sv[k] ^ expm) & TAGM;
                        if (diff == 0) break;
                        if (++spins > (1L << 20)) break; // bailout (never if correct)
                    }
                }
            }
            // unpack into hsh[par]: all writes 16B-lane-stride ds_write_b128
            {
                u32* hp = hshu + par * 8192;
#pragma unroll
                for (int r = 0; r < 4; r++) {
                    u32x4 vlo, vhi;
#pragma unroll
                    for (int j = 0; j < 4; j++) {
                        vlo[j] = (u32)sv[r * 4 + j];
                        vhi[j] = (u32)(sv[r * 4 + j] >> 32);
                    }
                    *(u32x4*)&hp[r * 1024 + st * 4] = vlo;
                    *(u32x4*)&hp[4096 + r * 1024 + st * 4] = vhi;
                }
            }
            // carry xv to A2 via registers (kept live across the barrier)
            if (wave >= 6 && t + 1 < 512) {
                wg_barrier(); // hsh[par] ready
                int npar = (t + 1) & 1;
                int c0 = xit, c1 = xit + 128, c2 = xit + 256;
                {
                    int plane = c0 / 192, rem = c0 % 192, row_ = rem / 12,
                        cw = rem % 12;
                    *(bf16x8*)&xsh[npar][plane][row_][(cw >> 2) * 32 + (cw & 3) * 8] =
                        xv0;
                }
                if (xlo_en || c1 < 192) {
                    int plane = c1 / 192, rem = c1 % 192, row_ = rem / 12,
                        cw = rem % 12;
                    *(bf16x8*)&xsh[npar][plane][row_][(cw >> 2) * 32 + (cw & 3) * 8] =
                        xv1;
                }
                if (xlo_en) {
                    int plane = 1, rem = c2 % 192, row_ = rem / 12, cw = rem % 12;
                    *(bf16x8*)&xsh[npar][plane][row_][(cw >> 2) * 32 + (cw & 3) * 8] =
                        xv2;
                }
            } else {
                wg_barrier(); // hsh[par] ready
            }
        } else {
            wg_barrier(); // hsh[par] ready (gate/MFMA waves arrive early)
        }
        // ===== A2: MFMA (waves 0-5); waves 6-7 did x ds_write above ==========
        if (wave < 6) {
            f32x4 aa = (f32x4){0.f, 0.f, 0.f, 0.f};
            f32x4 ab = (f32x4){0.f, 0.f, 0.f, 0.f};
            f32x4 ac = (f32x4){0.f, 0.f, 0.f, 0.f};
#pragma unroll
            for (int kk = 0; kk < 16; kk++) {
                bf16x8 ah = *(const bf16x8*)&hsh[par][0][kk][lane * 8];
                bf16x8 al = *(const bf16x8*)&hsh[par][1][kk][lane * 8];
                aa = MFMA16(ah, bh[kk], aa);
                ab = MFMA16(al, bh[kk], ab);
                ac = MFMA16(ah, bl[kk], ac);
            }
            f32x4 acc = aa + ab;
            acc = acc + ac;
            *(f32x4*)&pre[wave][lane & 15][(lane >> 4) * 4] = acc;
        }
        wg_barrier(); // pre + xsh[npar] ready
        // ===== B: gates (tid<256), fire-and-forget stores ====================
        if (tid < 256) {
            float hold[2] = {h0, h1};
            float hn[2];
#pragma unroll
            for (int j = 0; j < 2; j++) {
                int uu = 2 * q + j;
                int sl = uu >> 4, c16 = uu & 15;
                float xz = bf2f(xsh[par][0][grow][uu]);
                float xr = bf2f(xsh[par][0][grow][32 + uu]);
                float xh = bf2f(xsh[par][0][grow][64 + uu]);
                if (xlo_en) {
                    xz += bf2f(xsh[par][1][grow][uu]);
                    xr += bf2f(xsh[par][1][grow][32 + uu]);
                    xh += bf2f(xsh[par][1][grow][64 + uu]);
                }
                float rz = pre[sl][c16][grow] + rb[uu];
                float rr = pre[2 + sl][c16][grow] + rb[32 + uu];
                float rh = pre[4 + sl][c16][grow] + rb[64 + uu];
                float z = 1.f / (1.f + expf(-(xz + rz)));
                float r = 1.f / (1.f + expf(-(xr + rr)));
                float hh = tanhf(xh + r * rh);
                hn[j] = z * hold[j] + (1.f - z) * hh;
            }
            h0 = hn[0];
            h1 = hn[1];
            if (t < 511) {
                short hi0, lo0, hi1, lo1;
                split_bf(hn[0], hi0, lo0);
                split_bf(hn[1], hi1, lo1);
                const u32 tag = (u32)(t % 3) + 1;
                u32 lo0m = ((u32)(u16)lo0 & ~1u) | (tag & 1);
                u32 lo1m = ((u32)(u16)lo1 & ~1u) | ((tag >> 1) & 1);
                u64 v = (u64)(u16)hi0 | ((u64)(u16)hi1 << 16) | ((u64)lo0m << 32) |
                        ((u64)lo1m << 48);
                __hip_atomic_store(&hbuf2[((size_t)(par * 4 + g)) * 4096 + hslot], v,
                                   __ATOMIC_RELAXED, __HIP_MEMORY_SCOPE_AGENT);
            }
            *(f32x2*)&out[((size_t)(g * 16 + grow) * 512 + t) * 512 + w * 32 + 2 * q] =
                (f32x2){h0, h1};
        }
        // no loop-bottom barrier: hsh parity-double-buffered; pre/xsh
        // overwrites only happen after the NEXT bar1.
    }
}

extern "C" void kernel_launch(void* const* d_in, const int* in_sizes, int n_in,
                              void* d_out, int out_size, void* d_ws, size_t ws_size,
                              hipStream_t stream) {
    const float* inputs = (const float*)d_in[0]; // [64,512,512]
    const float* wk = (const float*)d_in[1];     // [512,1536]
    const float* wr = (const float*)d_in[2];     // [512,1536]
    const float* bias = (const float*)d_in[3];   // [2,1536]
    float* out = (float*)d_out;
    char* ws = (char*)d_ws;

    const size_t SZ_W = 512UL * 1536 * 2; // 1.5 MiB per plane
    short* wk_hi = (short*)(ws);
    short* wk_lo = (short*)(ws + SZ_W);
    short* wr_hi = (short*)(ws + 2 * SZ_W);
    short* wr_lo = (short*)(ws + 3 * SZ_W);
    u64* hbuf2 = (u64*)(ws + 4 * SZ_W); // 2 par x 4 grp x 4096 u64 = 256 KiB
    char* xbase = ws + 4 * SZ_W + 262144;
    const size_t SZ_X = 32768UL * 1536 * 2; // 96 MiB per plane
    __hip_bfloat16* xhi = (__hip_bfloat16*)xbase;
    __hip_bfloat16* xlo = (__hip_bfloat16*)(xbase + SZ_X);

    size_t need_min = (size_t)(xbase - ws) + SZ_X;
    size_t need_full = need_min + SZ_X;
    if (ws_size < need_min) return; // cannot run without scratch; fail visibly
    int xlo_en = (ws_size >= need_full) ? 1 : 0;

    zero_kernel<<<256, 256, 0, stream>>>((float*)hbuf2, 262144 / 4);
    pack_w_kernel<<<1536, 64, 0, stream>>>(wk, wk_hi, wk_lo);
    pack_w_kernel<<<1536, 64, 0, stream>>>(wr, wr_hi, wr_lo);
    xgemm_kernel<<<3072, 256, 0, stream>>>(inputs, wk_hi, wk_lo, bias, xhi, xlo, xlo_en);
    scan_kernel<<<64, 512, 0, stream>>>(xhi, xlo, wr_hi, wr_lo, bias, out, hbuf2,
                                        xlo_en);
}

// Round 12
// 2261.489 us; speedup vs baseline: 1.1299x; 1.1299x over previous
//
#include <hip/hip_runtime.h>
#include <hip/hip_bf16.h>

// GRU forward: B=64, T=512, I=512, U=512, out [B,T,U] fp32.
// Round 12 = recombination of the two measured-best components:
//  - scan_kernel: ROUND 10 version verbatim (2040us measured). Tag-in-data
//    protocol, 512 threads x 8 slots staging (sA/sB conflict-free split),
//    hsh parity-double-buffered, 2 raw barriers/step. r11's dedicated-poll
//    restructure regressed scan (+330us) and is reverted.
//  - xgemm_kernel: ROUND 11 version verbatim (-292us measured). 3072 blocks =
//    1024 row-pairs x 3 col-groups; each B-frag load feeds 6 MFMAs.
// Protocol recap: gates store h as one atomic u64 {hi0,hi1,lo0,lo1} with
// 2-bit tag (t%3)+1 in the two lo-bf16 LSBs (err<=2^-16), fire-and-forget;
// consumers spin on their 8 slots until tags match -> detect IS the load.
// Raw s_barrier + lgkmcnt(0) only (no vmcnt drain on any barrier).
// __launch_bounds__(512,1) so the R-slice stays register/AGPR-resident.

typedef float f32x4 __attribute__((ext_vector_type(4)));
typedef float f32x2 __attribute__((ext_vector_type(2)));
typedef short bf16x8 __attribute__((ext_vector_type(8)));
typedef unsigned long long u64;
typedef unsigned int u32;
typedef unsigned short u16;
typedef u32 u32x4 __attribute__((ext_vector_type(4)));

#define MFMA16(a, b, c) __builtin_amdgcn_mfma_f32_16x16x32_bf16((a), (b), (c), 0, 0, 0)

__device__ __forceinline__ float bf2f(__hip_bfloat16 v) { return __bfloat162float(v); }

__device__ __forceinline__ void split_bf(float v, short& hi, short& lo) {
    __hip_bfloat16 h = __float2bfloat16(v);
    float rem = v - __bfloat162float(h);
    __hip_bfloat16 l = __float2bfloat16(rem);
    hi = __builtin_bit_cast(short, h);
    lo = __builtin_bit_cast(short, l);
}

// Raw barrier: LDS-drain only. No vmcnt drain (that's the point).
__device__ __forceinline__ void wg_barrier() {
    __builtin_amdgcn_sched_barrier(0);
    asm volatile("s_waitcnt lgkmcnt(0)" ::: "memory");
    __builtin_amdgcn_s_barrier();
    __builtin_amdgcn_sched_barrier(0);
}

// ---------------------------------------------------------------- zero scratch
__global__ void zero_kernel(float* p, int n) {
    int i = blockIdx.x * blockDim.x + threadIdx.x;
    int stride = gridDim.x * blockDim.x;
    for (; i < n; i += stride) p[i] = 0.f;
}

// ------------------------------------------------- pack weights into B-frags
// Source W [512 x 1536] fp32. Frag (tile,kk): lane l element e =
// W[kk*32 + 8*(l>>4) + e][tile*16 + (l&15)], stored hi/lo bf16 planes.
__global__ __launch_bounds__(64, 1) void pack_w_kernel(const float* __restrict__ W,
                                                       short* __restrict__ dhi,
                                                       short* __restrict__ dlo) {
    int bid = blockIdx.x;   // tile*16 + kk, 0..1535
    int lane = threadIdx.x; // 0..63
    int col = (bid >> 4) * 16 + (lane & 15);
    int kbase = (bid & 15) * 32 + (lane >> 4) * 8;
    bf16x8 vh, vl;
#pragma unroll
    for (int e = 0; e < 8; e++) {
        float v = W[(kbase + e) * 1536 + col];
        short h, l;
        split_bf(v, h, l);
        vh[e] = h;
        vl[e] = l;
    }
    *(bf16x8*)(dhi + bid * 512 + lane * 8) = vh;
    *(bf16x8*)(dlo + bid * 512 + lane * 8) = vl;
}

// ------------------------------------------------------------- x_all GEMM
// 3072 blocks = 1024 row-pairs x 3 col-groups. Block: rows rp*32..+31,
// cols cg*512..+511. Wave: 2 row-tiles x 8 col-tiles; each B-frag load feeds
// 6 MFMAs (2 rows x 3 hi/lo passes).
__global__ __launch_bounds__(256, 2) void xgemm_kernel(
    const float* __restrict__ A, const short* __restrict__ wkh,
    const short* __restrict__ wkl, const float* __restrict__ bias,
    __hip_bfloat16* __restrict__ xhi, __hip_bfloat16* __restrict__ xlo, int xlo_en) {
    int bid = blockIdx.x; // 0..3071
    int cg = bid % 3;
    int rp = bid / 3;
    int wave = threadIdx.x >> 6, lane = threadIdx.x & 63;
    int arow0 = rp * 32 + (lane & 15);
    const float* ab0 = A + (size_t)arow0 * 512 + (lane >> 4) * 8;
    const float* ab1 = ab0 + 16 * 512;

    f32x4 acc[2][8];
#pragma unroll
    for (int r = 0; r < 2; r++)
#pragma unroll
        for (int j = 0; j < 8; j++) acc[r][j] = (f32x4){0.f, 0.f, 0.f, 0.f};

#pragma unroll 1
    for (int kk = 0; kk < 16; kk++) {
        f32x4 a00 = *(const f32x4*)(ab0 + kk * 32);
        f32x4 a01 = *(const f32x4*)(ab0 + kk * 32 + 4);
        f32x4 a10 = *(const f32x4*)(ab1 + kk * 32);
        f32x4 a11 = *(const f32x4*)(ab1 + kk * 32 + 4);
        bf16x8 ah0, al0, ah1, al1;
#pragma unroll
        for (int e = 0; e < 8; e++) {
            float v0 = (e < 4) ? a00[e] : a01[e - 4];
            float v1 = (e < 4) ? a10[e] : a11[e - 4];
            short h, l;
            split_bf(v0, h, l);
            ah0[e] = h;
            al0[e] = l;
            split_bf(v1, h, l);
            ah1[e] = h;
            al1[e] = l;
        }
#pragma unroll
        for (int j = 0; j < 8; j++) {
            int frag = (cg * 32 + wave * 8 + j) * 16 + kk;
            bf16x8 bh = *(const bf16x8*)(wkh + frag * 512 + lane * 8);
            bf16x8 bl = *(const bf16x8*)(wkl + frag * 512 + lane * 8);
            acc[0][j] = MFMA16(ah0, bh, acc[0][j]);
            acc[0][j] = MFMA16(al0, bh, acc[0][j]);
            acc[0][j] = MFMA16(ah0, bl, acc[0][j]);
            acc[1][j] = MFMA16(ah1, bh, acc[1][j]);
            acc[1][j] = MFMA16(al1, bh, acc[1][j]);
            acc[1][j] = MFMA16(ah1, bl, acc[1][j]);
        }
    }
    int colin = lane & 15, r4 = (lane >> 4) * 4;
#pragma unroll
    for (int j = 0; j < 8; j++) {
        int colg = (cg * 32 + wave * 8 + j) * 16 + colin;
        float bv = bias[colg];
#pragma unroll
        for (int rt = 0; rt < 2; rt++) {
#pragma unroll
            for (int r = 0; r < 4; r++) {
                float v = acc[rt][j][r] + bv;
                int rowg = rp * 32 + rt * 16 + r4 + r;
                short h, l;
                split_bf(v, h, l);
                xhi[(size_t)rowg * 1536 + colg] = __builtin_bit_cast(__hip_bfloat16, h);
                if (xlo_en)
                    xlo[(size_t)rowg * 1536 + colg] =
                        __builtin_bit_cast(__hip_bfloat16, l);
            }
        }
    }
}

// ------------------------------------------------------------------ scan
// hbuf2 layout: [par(2)][group(4)][4096 u64]; slot s within a group:
// chunk=s>>8 (peer WG w), lane'=(s>>2)&63, epair=s&3. u64 = {hi0,hi1,lo0,lo1}
// for (row=lane'&15, units 32*chunk + 8*(lane'>>4) + 2*epair..+1), tag bits
// in lo0/lo1 LSBs. hsh u32 view: hshu[par*8192 + plane*4096 + s].
__global__ __launch_bounds__(512, 1) void scan_kernel(
    const __hip_bfloat16* __restrict__ xhi, const __hip_bfloat16* __restrict__ xlo,
    const short* __restrict__ wrh, const short* __restrict__ wrl,
    const float* __restrict__ bias, float* __restrict__ out,
    u64* hbuf2, int xlo_en) {
    const int bid = blockIdx.x;
    const int g = bid & 3;
    const int w = bid >> 2;
    const int tid = threadIdx.x;
    const int wave = tid >> 6;
    const int lane = tid & 63;

    __shared__ __align__(16) float pre[6][16][16];
    __shared__ __align__(16) __hip_bfloat16 xsh[2][2][16][104]; // [par][plane]
    __shared__ __align__(16) __hip_bfloat16 hsh[2][2][16][512]; // [par][plane][kk][frag]
    __shared__ float rb[96];

    if (tid < 96) rb[tid] = bias[1536 + (tid >> 5) * 512 + w * 32 + (tid & 31)];

    // persistent B fragments (hi+lo) for waves 0-5 (LB(512,1): stays resident)
    bf16x8 bh[16], bl[16];
    if (wave < 6) {
        int tile = (wave >> 1) * 32 + 2 * w + (wave & 1);
#pragma unroll
        for (int kk = 0; kk < 16; kk++) {
            bh[kk] = *(const bf16x8*)(wrh + (tile * 16 + kk) * 512 + lane * 8);
            bl[kk] = *(const bf16x8*)(wrl + (tile * 16 + kk) * 512 + lane * 8);
        }
#pragma unroll
        for (int kk = 0; kk < 16; kk++) {
            asm volatile("" : "+v"(bh[kk]), "+v"(bl[kk])); // defeat remat
        }
    } else {
        // x[0] prefetch straight into xsh[0]
        int it0 = tid - 384; // 0..127
        int nch = xlo_en ? 384 : 192;
        for (int c = it0; c < nch; c += 128) {
            int plane = c / 192, rem = c % 192;
            int row_ = rem / 12, cw = rem % 12;
            const __hip_bfloat16* src = (plane ? xlo : xhi) +
                                        (size_t)((g * 16 + row_) * 512) * 1536 +
                                        (cw >> 2) * 512 + w * 32 + (cw & 3) * 8;
            *(bf16x8*)&xsh[0][plane][row_][(cw >> 2) * 32 + (cw & 3) * 8] =
                *(const bf16x8*)src;
        }
    }

    const int grow = tid & 15; // gate thread: batch row
    const int q = tid >> 4;    // gate thread: unit pair 0..15 (tid<256)
    float h0 = 0.f, h1 = 0.f;
    const int hslot = w * 256 + (grow + 16 * (q >> 2)) * 4 + (q & 3);
    const int sA = tid * 4;        // staging slots [sA, sA+4)
    const int sB = 2048 + tid * 4; // staging slots [sB, sB+4)
    const int xit = tid - 384;     // x-prefetch thread index (waves 6-7)

    u32* hshu = (u32*)hsh;

    __syncthreads();

    for (int t = 0; t < 512; t++) {
        const int par = t & 1;
        // ================= A1: staged, tag-validated h load =================
        u64 sv[8];
        {
            const u64* gb = hbuf2 + ((size_t)(((t - 1) & 1) * 4 + g)) * 4096;
            if (t == 0) {
#pragma unroll
                for (int j = 0; j < 4; j++)
                    sv[j] = __hip_atomic_load(gb + sA + j, __ATOMIC_RELAXED,
                                              __HIP_MEMORY_SCOPE_AGENT);
#pragma unroll
                for (int j = 0; j < 4; j++)
                    sv[4 + j] = __hip_atomic_load(gb + sB + j, __ATOMIC_RELAXED,
                                                  __HIP_MEMORY_SCOPE_AGENT);
            } else {
                const int expv = ((t - 1) % 3) + 1;
                const u64 expm =
                    ((u64)(expv & 1) << 32) | ((u64)((expv >> 1) & 1) << 48);
                const u64 TAGM = (1ULL << 32) | (1ULL << 48);
                long spins = 0;
                while (true) {
#pragma unroll
                    for (int j = 0; j < 4; j++)
                        sv[j] = __hip_atomic_load(gb + sA + j, __ATOMIC_RELAXED,
                                                  __HIP_MEMORY_SCOPE_AGENT);
#pragma unroll
                    for (int j = 0; j < 4; j++)
                        sv[4 + j] = __hip_atomic_load(gb + sB + j, __ATOMIC_RELAXED,
                                                      __HIP_MEMORY_SCOPE_AGENT);
                    u64 diff = 0;
#pragma unroll
                    for (int j = 0; j < 8; j++) diff |= (sv[j] ^ expm) & TAGM;
                    if (diff == 0) break;
                    if (++spins > (1L << 20)) break; // bailout (never hit if correct)
                }
            }
        }
        // x[t+1] loads issued here (latency hides under spin/unpack/MFMA)
        bf16x8 xv0, xv1, xv2;
        if (wave >= 6 && t + 1 < 512) {
            int c0 = xit, c1 = xit + 128, c2 = xit + 256;
            {
                int plane = c0 / 192, rem = c0 % 192, row_ = rem / 12, cw = rem % 12;
                xv0 = *(const bf16x8*)((plane ? xlo : xhi) +
                                       (size_t)((g * 16 + row_) * 512 + (t + 1)) * 1536 +
                                       (cw >> 2) * 512 + w * 32 + (cw & 3) * 8);
            }
            if (xlo_en || c1 < 192) {
                int plane = c1 / 192, rem = c1 % 192, row_ = rem / 12, cw = rem % 12;
                xv1 = *(const bf16x8*)((plane ? xlo : xhi) +
                                       (size_t)((g * 16 + row_) * 512 + (t + 1)) * 1536 +
                                       (cw >> 2) * 512 + w * 32 + (cw & 3) * 8);
            }
            if (xlo_en) {
                int plane = 1, rem = c2 % 192, row_ = rem / 12, cw = rem % 12;
                xv2 = *(const bf16x8*)((plane ? xlo : xhi) +
                                       (size_t)((g * 16 + row_) * 512 + (t + 1)) * 1536 +
                                       (cw >> 2) * 512 + w * 32 + (cw & 3) * 8);
            }
        }
        // unpack staged u64s into hsh[par]: all writes 16B-lane-stride b128
        {
            u32* hp = hshu + par * 8192;
            u32x4 a0, a1, b0, b1;
#pragma unroll
            for (int j = 0; j < 4; j++) {
                a0[j] = (u32)sv[j];
                b0[j] = (u32)(sv[j] >> 32);
                a1[j] = (u32)sv[4 + j];
                b1[j] = (u32)(sv[4 + j] >> 32);
            }
            *(u32x4*)&hp[sA] = a0;
            *(u32x4*)&hp[sB] = a1;
            *(u32x4*)&hp[4096 + sA] = b0;
            *(u32x4*)&hp[4096 + sB] = b1;
        }
        wg_barrier(); // hsh[par] ready
        // ================= A2: MFMA (waves 0-5) / x ds_write (6-7) ==========
        if (wave < 6) {
            f32x4 aa = (f32x4){0.f, 0.f, 0.f, 0.f};
            f32x4 ab = (f32x4){0.f, 0.f, 0.f, 0.f};
            f32x4 ac = (f32x4){0.f, 0.f, 0.f, 0.f};
#pragma unroll
            for (int kk = 0; kk < 16; kk++) {
                bf16x8 ah = *(const bf16x8*)&hsh[par][0][kk][lane * 8];
                bf16x8 al = *(const bf16x8*)&hsh[par][1][kk][lane * 8];
                aa = MFMA16(ah, bh[kk], aa);
                ab = MFMA16(al, bh[kk], ab);
                ac = MFMA16(ah, bl[kk], ac);
            }
            f32x4 acc = aa + ab;
            acc = acc + ac;
            *(f32x4*)&pre[wave][lane & 15][(lane >> 4) * 4] = acc;
        } else if (t + 1 < 512) {
            int npar = (t + 1) & 1;
            int c0 = xit, c1 = xit + 128, c2 = xit + 256;
            {
                int plane = c0 / 192, rem = c0 % 192, row_ = rem / 12, cw = rem % 12;
                *(bf16x8*)&xsh[npar][plane][row_][(cw >> 2) * 32 + (cw & 3) * 8] = xv0;
            }
            if (xlo_en || c1 < 192) {
                int plane = c1 / 192, rem = c1 % 192, row_ = rem / 12, cw = rem % 12;
                *(bf16x8*)&xsh[npar][plane][row_][(cw >> 2) * 32 + (cw & 3) * 8] = xv1;
            }
            if (xlo_en) {
                int plane = 1, rem = c2 % 192, row_ = rem / 12, cw = rem % 12;
                *(bf16x8*)&xsh[npar][plane][row_][(cw >> 2) * 32 + (cw & 3) * 8] = xv2;
            }
        }
        wg_barrier(); // pre + xsh[npar] ready
        // ================= B: gates (tid<256), fire-and-forget stores =======
        if (tid < 256) {
            float hold[2] = {h0, h1};
            float hn[2];
#pragma unroll
            for (int j = 0; j < 2; j++) {
                int uu = 2 * q + j;
                int sl = uu >> 4, c16 = uu & 15;
                float xz = bf2f(xsh[par][0][grow][uu]);
                float xr = bf2f(xsh[par][0][grow][32 + uu]);
                float xh = bf2f(xsh[par][0][grow][64 + uu]);
                if (xlo_en) {
                    xz += bf2f(xsh[par][1][grow][uu]);
                    xr += bf2f(xsh[par][1][grow][32 + uu]);
                    xh += bf2f(xsh[par][1][grow][64 + uu]);
                }
                float rz = pre[sl][c16][grow] + rb[uu];
                float rr = pre[2 + sl][c16][grow] + rb[32 + uu];
                float rh = pre[4 + sl][c16][grow] + rb[64 + uu];
                float z = 1.f / (1.f + expf(-(xz + rz)));
                float r = 1.f / (1.f + expf(-(xr + rr)));
                float hh = tanhf(xh + r * rh);
                hn[j] = z * hold[j] + (1.f - z) * hh;
            }
            h0 = hn[0];
            h1 = hn[1];
            if (t < 511) {
                short hi0, lo0, hi1, lo1;
                split_bf(hn[0], hi0, lo0);
                split_bf(hn[1], hi1, lo1);
                const u32 tag = (u32)(t % 3) + 1;
                u32 lo0m = ((u32)(u16)lo0 & ~1u) | (tag & 1);
                u32 lo1m = ((u32)(u16)lo1 & ~1u) | ((tag >> 1) & 1);
                u64 v = (u64)(u16)hi0 | ((u64)(u16)hi1 << 16) | ((u64)lo0m << 32) |
                        ((u64)lo1m << 48);
                __hip_atomic_store(&hbuf2[((size_t)(par * 4 + g)) * 4096 + hslot], v,
                                   __ATOMIC_RELAXED, __HIP_MEMORY_SCOPE_AGENT);
            }
            *(f32x2*)&out[((size_t)(g * 16 + grow) * 512 + t) * 512 + w * 32 + 2 * q] =
                (f32x2){h0, h1};
        }
        // no loop-bottom barrier: hsh is parity-double-buffered; pre/xsh
        // overwrites only happen after the NEXT bar1, which gate waves reach
        // only after finishing this B phase.
    }
}

extern "C" void kernel_launch(void* const* d_in, const int* in_sizes, int n_in,
                              void* d_out, int out_size, void* d_ws, size_t ws_size,
                              hipStream_t stream) {
    const float* inputs = (const float*)d_in[0]; // [64,512,512]
    const float* wk = (const float*)d_in[1];     // [512,1536]
    const float* wr = (const float*)d_in[2];     // [512,1536]
    const float* bias = (const float*)d_in[3];   // [2,1536]
    float* out = (float*)d_out;
    char* ws = (char*)d_ws;

    const size_t SZ_W = 512UL * 1536 * 2; // 1.5 MiB per plane
    short* wk_hi = (short*)(ws);
    short* wk_lo = (short*)(ws + SZ_W);
    short* wr_hi = (short*)(ws + 2 * SZ_W);
    short* wr_lo = (short*)(ws + 3 * SZ_W);
    u64* hbuf2 = (u64*)(ws + 4 * SZ_W); // 2 par x 4 grp x 4096 u64 = 256 KiB
    char* xbase = ws + 4 * SZ_W + 262144;
    const size_t SZ_X = 32768UL * 1536 * 2; // 96 MiB per plane
    __hip_bfloat16* xhi = (__hip_bfloat16*)xbase;
    __hip_bfloat16* xlo = (__hip_bfloat16*)(xbase + SZ_X);

    size_t need_min = (size_t)(xbase - ws) + SZ_X;
    size_t need_full = need_min + SZ_X;
    if (ws_size < need_min) return; // cannot run without scratch; fail visibly
    int xlo_en = (ws_size >= need_full) ? 1 : 0;

    zero_kernel<<<256, 256, 0, stream>>>((float*)hbuf2, 262144 / 4);
    pack_w_kernel<<<1536, 64, 0, stream>>>(wk, wk_hi, wk_lo);
    pack_w_kernel<<<1536, 64, 0, stream>>>(wr, wr_hi, wr_lo);
    xgemm_kernel<<<3072, 256, 0, stream>>>(inputs, wk_hi, wk_lo, bias, xhi, xlo, xlo_en);
    scan_kernel<<<64, 512, 0, stream>>>(xhi, xlo, wr_hi, wr_lo, bias, out, hbuf2,
                                        xlo_en);
}